// Round 1
// baseline (339.100 us; speedup 1.0000x reference)
//
#include <hip/hip_runtime.h>
#include <stdint.h>

#define NNODES 100000
#define NEDGES 100000
#define DIM    256
#define NCH    4          // 2 side + 2 rel
#define ET     64         // edges per block (was 32): halves per-edge B-table L2 traffic
#define RSF    264        // fp16 per staged row (256 + 8 pad; 264*2B=528B)
#define CONVB  2048       // grid-stride conversion blocks

typedef _Float16 f16x8 __attribute__((ext_vector_type(8)));
typedef _Float16 f16x4 __attribute__((ext_vector_type(4)));
typedef float f32x4  __attribute__((ext_vector_type(4)));

// ---------------------------------------------------------------------------
// Fused prep (single launch):
//  blocks [0,128): build the 4 fused/transposed channel matrices in MFMA
//    B-fragment order, split into fp16 hi/lo (22-bit effective).
//  blocks [128, 128+CONVB): convert h (f32, 102.4 MB) -> fp16 (51.2 MB).
//    Grid-stride, fully-dense addressing: each load instr covers 1 KB/wave
//    (lane-contiguous f32x4), 4 loads in flight per thread via manual 4x
//    unroll. Old version gave each thread 48 B total (half-dense 32B-stride
//    loads) -> ~1 TB/s; this should run at HBM rate (~25-30 us).
// ---------------------------------------------------------------------------
__global__ void prep_fused(const float* __restrict__ RW,
                           const float* __restrict__ dside,
                           const float* __restrict__ Wrel,
                           const float* __restrict__ h,
                           _Float16* __restrict__ Bh, _Float16* __restrict__ Bl,
                           _Float16* __restrict__ H16) {
    if (blockIdx.x < 128) {
        int t = blockIdx.x * blockDim.x + threadIdx.x;   // < 32768
        int lane = t & 63;
        int ft   = (t >> 6) & 15;
        int kc   = (t >> 10) & 7;
        int c    = t >> 13;
        int quad = lane >> 4, col = lane & 15;
        int f     = ft * 16 + col;
        int kbase = kc * 32 + quad * 8;

        f16x8 vh, vl;
#pragma unroll
        for (int j = 0; j < 8; ++j) {
            int k = kbase + j;
            float val;
            if (c < 2) {
                val = dside[c * DIM + f] * RW[f * DIM + k] * dside[c * DIM + k];
            } else {
                val = Wrel[(size_t)(c - 2) * DIM * DIM + f * DIM + k];
            }
            _Float16 hi = (_Float16)val;
            vh[j] = hi;
            vl[j] = (_Float16)(val - (float)hi);
        }
        ((f16x8*)Bh)[t] = vh;
        ((f16x8*)Bl)[t] = vl;
    } else {
        const int total4 = NNODES * DIM / 4;   // 6.4e6 f32x4 chunks
        const int stride = CONVB * 256;
        int i = (blockIdx.x - 128) * 256 + (int)threadIdx.x;
        const f32x4* s4 = (const f32x4*)h;
        f16x4* d4 = (f16x4*)H16;
        for (; i + 3 * stride < total4; i += 4 * stride) {
            f32x4 a  = s4[i];
            f32x4 b  = s4[i + stride];
            f32x4 cc = s4[i + 2 * stride];
            f32x4 d  = s4[i + 3 * stride];
            f16x4 oa, ob, oc, od;
#pragma unroll
            for (int j = 0; j < 4; ++j) {
                oa[j] = (_Float16)a[j];  ob[j] = (_Float16)b[j];
                oc[j] = (_Float16)cc[j]; od[j] = (_Float16)d[j];
            }
            d4[i] = oa; d4[i + stride] = ob;
            d4[i + 2 * stride] = oc; d4[i + 3 * stride] = od;
        }
        for (; i < total4; i += stride) {
            f32x4 a = s4[i];
            f16x4 o;
#pragma unroll
            for (int j = 0; j < 4; ++j) o[j] = (_Float16)a[j];
            d4[i] = o;
        }
    }
}

// ---------------------------------------------------------------------------
// Fused edge kernel. ET=64 edges per 512-thread block (8 waves):
//  - per-block B-table read is the FULL channel slice (256 KB) regardless of
//    ET, so doubling ET halves total B L2 traffic: 3.2 GB -> 1.6 GB (~46 us
//    of L2 pressure removed; L2 was >50% busy on B re-reads alone).
//  - 8 waves partition the 16 f-tiles 2-per-wave; each wave owns all 4
//    M-tiles (64 edge rows). acc = f32x4[4][2] = 32 VGPRs, same as before.
//  - V (dst) rows prefetched into registers BEFORE the K-loop: their gather
//    latency hides under 128 MFMAs instead of stalling at a barrier.
// LDS ~36.4 KB -> up to 4 blocks/CU by LDS; 2048-thread cap -> 4 blocks/CU.
// ---------------------------------------------------------------------------
__global__ __launch_bounds__(512, 2)
void edge_kernel(const _Float16* __restrict__ H16,
                 const int* __restrict__ src_idx,
                 const int* __restrict__ dst_idx,
                 const float* __restrict__ brel,
                 const _Float16* __restrict__ Bh_sw,
                 const _Float16* __restrict__ Bl_sw,
                 float* __restrict__ out) {
    const int c    = blockIdx.y;
    const int e0   = blockIdx.x * ET;
    const int tid  = threadIdx.x;
    const int w    = tid >> 6;          // 0..7
    const int lane = tid & 63;
    const int quad = lane >> 4, col = lane & 15;

    __shared__ __align__(16) _Float16 s_row[ET * RSF];   // 33,792 B
    __shared__ uint32_t s_src[ET];
    __shared__ uint32_t s_dst[ET];
    __shared__ float    red[8][ET];                      // 2 KB

    if (tid < ET) {
        int idx = e0 + tid;
        int si = 0, di = 0;
        if (idx < NEDGES) {
            si = src_idx[(size_t)c * NEDGES + idx];
            di = dst_idx[(size_t)c * NEDGES + idx];
        }
        s_src[tid] = (uint32_t)si;
        s_dst[tid] = (uint32_t)di;
    }
    __syncthreads();

    // ---- Stage A: wave w gathers rows w*8..w*8+7 (512 B coalesced each);
    //      V rows prefetched into registers (latency hidden under K-loop) ----
    f16x4 aR[8], vR[8];
#pragma unroll
    for (int i = 0; i < 8; ++i) {
        int lr = w * 8 + i;
        aR[i] = *(const f16x4*)(H16 + (size_t)s_src[lr] * DIM + lane * 4);
    }
#pragma unroll
    for (int i = 0; i < 8; ++i) {
        int lr = w * 8 + i;
        vR[i] = *(const f16x4*)(H16 + (size_t)s_dst[lr] * DIM + lane * 4);
    }
#pragma unroll
    for (int i = 0; i < 8; ++i) {
        int lr = w * 8 + i;
        *(f16x4*)&s_row[lr * RSF + lane * 4] = aR[i];
    }
    __syncthreads();

    // ---- K-loop: A from LDS (direct fragment reads), 2-term f16 MFMA ----
    f32x4 acc[4][2];
#pragma unroll
    for (int mt = 0; mt < 4; ++mt)
#pragma unroll
        for (int ft = 0; ft < 2; ++ft) acc[mt][ft] = (f32x4){0.f, 0.f, 0.f, 0.f};

    const f16x8* Bh = (const f16x8*)Bh_sw;
    const f16x8* Bl = (const f16x8*)Bl_sw;

#pragma unroll
    for (int kc = 0; kc < 8; ++kc) {
        f16x8 A[4];
#pragma unroll
        for (int mt = 0; mt < 4; ++mt)
            A[mt] = *(const f16x8*)&s_row[(mt * 16 + col) * RSF + kc * 32 + quad * 8];

        int fb = ((c * 8 + kc) * 16 + w * 2) * 64 + lane;
#pragma unroll
        for (int ft = 0; ft < 2; ++ft) {
            f16x8 bh = Bh[fb + ft * 64];
            f16x8 bl = Bl[fb + ft * 64];
#pragma unroll
            for (int mt = 0; mt < 4; ++mt) {
                acc[mt][ft] = __builtin_amdgcn_mfma_f32_16x16x32_f16(A[mt], bh, acc[mt][ft], 0, 0, 0);
                acc[mt][ft] = __builtin_amdgcn_mfma_f32_16x16x32_f16(A[mt], bl, acc[mt][ft], 0, 0, 0);
            }
        }
    }
    __syncthreads();   // all waves done reading A from s_row

    // ---- Stage V: write prefetched dst rows into same LDS ----
#pragma unroll
    for (int i = 0; i < 8; ++i) {
        int lr = w * 8 + i;
        *(f16x4*)&s_row[lr * RSF + lane * 4] = vR[i];
    }
    __syncthreads();

    // ---- Epilogue: score_e = sum_f (C[e][f] + bias[f]) * V[e][f] ----
    // C/D layout: row(e) = quad*4 + reg, col(f) = lane&15.
    float bias[2];
#pragma unroll
    for (int ft = 0; ft < 2; ++ft) {
        int f = w * 32 + ft * 16 + col;
        bias[ft] = (c >= 2) ? brel[(size_t)(c - 2) * DIM + f] : 0.f;
    }

    float psum[4][4];  // [mt][r]
#pragma unroll
    for (int mt = 0; mt < 4; ++mt) {
#pragma unroll
        for (int r = 0; r < 4; ++r) {
            int el = mt * 16 + quad * 4 + r;
            float s = 0.f;
#pragma unroll
            for (int ft = 0; ft < 2; ++ft) {
                int f = w * 32 + ft * 16 + col;
                float v = (float)s_row[el * RSF + f];
                s += (acc[mt][ft][r] + bias[ft]) * v;
            }
            psum[mt][r] = s;
        }
    }

    // Reduce across the 16 f-columns (xor lane bits 0..3)
#pragma unroll
    for (int off = 1; off < 16; off <<= 1) {
#pragma unroll
        for (int mt = 0; mt < 4; ++mt)
#pragma unroll
            for (int r = 0; r < 4; ++r)
                psum[mt][r] += __shfl_xor(psum[mt][r], off, 64);
    }
    if (col == 0) {
#pragma unroll
        for (int mt = 0; mt < 4; ++mt)
#pragma unroll
            for (int r = 0; r < 4; ++r)
                red[w][mt * 16 + quad * 4 + r] = psum[mt][r];
    }
    __syncthreads();

    if (tid < ET) {
        int idx = e0 + tid;
        if (idx < NEDGES) {
            float s = 0.f;
#pragma unroll
            for (int i = 0; i < 8; ++i) s += red[i][tid];
            out[(size_t)c * NEDGES + idx] = s;
        }
    }
}

extern "C" void kernel_launch(void* const* d_in, const int* in_sizes, int n_in,
                              void* d_out, int out_size, void* d_ws, size_t ws_size,
                              hipStream_t stream) {
    const float* hmat  = (const float*)d_in[0];
    const int*   src   = (const int*)d_in[1];
    const int*   dst   = (const int*)d_in[2];
    const float* RW    = (const float*)d_in[3];
    const float* dside = (const float*)d_in[4];
    const float* Wrel  = (const float*)d_in[5];
    const float* brel  = (const float*)d_in[6];
    float* out = (float*)d_out;

    // Workspace: Bh (512 KB) | Bl (512 KB) | H16 (51.2 MB)
    const size_t nB = (size_t)NCH * DIM * DIM;   // fp16 per table
    _Float16* Bh  = (_Float16*)d_ws;
    _Float16* Bl  = Bh + nB;
    _Float16* H16 = Bl + nB;

    prep_fused<<<dim3(128 + CONVB), dim3(256), 0, stream>>>(
        RW, dside, Wrel, hmat, Bh, Bl, H16);

    dim3 grid((NEDGES + ET - 1) / ET, NCH);
    edge_kernel<<<grid, dim3(512), 0, stream>>>(H16, src, dst, brel, Bh, Bl, out);
}